// Round 16
// baseline (156.295 us; speedup 1.0000x reference)
//
#include <hip/hip_runtime.h>
#include <stdint.h>

#define HH 10
#define DD 64
#define LL 4096
#define CC 640
#define KVL 8192
#define ALPHA 0.42f
#define SC2 0.1803368801111204f  // (1/sqrt(64)) * log2(e)

typedef __attribute__((ext_vector_type(8))) short s16x8;
typedef __attribute__((ext_vector_type(4))) float f32x4;

__device__ inline ushort f2bf(float f) {
  uint32_t u = __builtin_bit_cast(uint32_t, f);
  u += 0x7FFFu + ((u >> 16) & 1u);   // RNE
  return (ushort)(u >> 16);
}

__device__ inline float bf2f(ushort u) {
  uint32_t x = (uint32_t)u << 16;
  return __builtin_bit_cast(float, x);
}

__device__ inline uint cvtpk(float lo, float hi) {
  uint r;
  asm("v_cvt_pk_bf16_f32 %0, %1, %2" : "=v"(r) : "v"(lo), "v"(hi));
  return r;
}

__device__ inline float fexp2(float x) {
  float r;
  asm("v_exp_f32 %0, %1" : "=v"(r) : "v"(x));  // pure, schedulable
  return r;
}

__device__ inline void gl16(const ushort* g, ushort* l) {
  __builtin_amdgcn_global_load_lds(
      (const __attribute__((address_space(1))) uint32_t*)g,
      (__attribute__((address_space(3))) uint32_t*)l, 16, 0, 0);
}

__device__ inline void bar() {
  __builtin_amdgcn_sched_barrier(0);
  __builtin_amdgcn_s_barrier();
  __builtin_amdgcn_sched_barrier(0);
}

// V^T tile column position for kv-local row kl (0..63), matching the
// register layout of the swapped-QK^T P fragment (see k_attn):
// A-slot s=8*lg+m (within 32-block k0) must hold kv = 32*k0+16*(m>>2)+4*lg+(m&3).
// Inverse: p = (kl&32) | ((kl&12)<<1) | ((kl&16)>>2) | (kl&3)
__device__ inline int vpos(int kl) {
  return (kl & 32) | ((kl & 12) << 1) | ((kl & 16) >> 2) | (kl & 3);
}

// ---------------- prep: hs fp32 -> bf16 ----------------
__global__ void k_cvt_hs(const float* __restrict__ in, ushort* __restrict__ out, int n4) {
  int i = blockIdx.x * blockDim.x + threadIdx.x;
  if (i < n4) {
    float4 v = ((const float4*)in)[i];
    ushort4 o;
    o.x = f2bf(v.x); o.y = f2bf(v.y); o.z = f2bf(v.z); o.w = f2bf(v.w);
    ((ushort4*)out)[i] = o;
  }
}

// ---------------- prep: 4x W [K][N] fp32 -> WT [N][K] bf16 (z-batched) ----------------
__global__ void k_wT4(const float* __restrict__ W0, const float* __restrict__ W1,
                      const float* __restrict__ W2, const float* __restrict__ W3,
                      ushort* __restrict__ WT) {
  __shared__ ushort t[64][65];
  const float* W = blockIdx.z == 0 ? W0 : blockIdx.z == 1 ? W1 : blockIdx.z == 2 ? W2 : W3;
  ushort* dst = WT + (size_t)blockIdx.z * CC * CC;
  int k0 = blockIdx.x * 64, n0 = blockIdx.y * 64;
  int tid = threadIdx.x;
#pragma unroll
  for (int i = 0; i < 4; ++i) {
    int id = tid + i * 256;
    int r = id >> 4, c4 = id & 15;
    float4 v = *(const float4*)(W + (size_t)(k0 + r) * CC + n0 + c4 * 4);
    t[r][c4 * 4 + 0] = f2bf(v.x);
    t[r][c4 * 4 + 1] = f2bf(v.y);
    t[r][c4 * 4 + 2] = f2bf(v.z);
    t[r][c4 * 4 + 3] = f2bf(v.w);
  }
  __syncthreads();
#pragma unroll
  for (int i = 0; i < 2; ++i) {
    int id = tid + i * 256;
    int n = id >> 3, cc = id & 7;
    ushort tmp[8];
#pragma unroll
    for (int j = 0; j < 8; ++j) tmp[j] = t[cc * 8 + j][n];
    *(uint4*)(dst + (size_t)(n0 + n) * CC + k0 + cc * 8) = *(uint4*)tmp;
  }
}

// ---------------- prep: background KV (rows L..KVL-1) ----------------
__global__ void k_cvt_bg(const float* __restrict__ Kbg, const float* __restrict__ Vbg,
                         ushort* __restrict__ kb, ushort* __restrict__ vbT, int n4) {
  int i = blockIdx.x * blockDim.x + threadIdx.x;
  if (i >= n4) return;
  int e = i * 4;
  int h = e / (LL * DD);
  int rem = e - h * (LL * DD);
  int kvl = rem >> 6;        // local row 0..4095
  int d0 = rem & 63;         // multiple of 4
  int kv = LL + kvl;         // global kv row
  float4 kf = ((const float4*)Kbg)[i];
  float4 vf = ((const float4*)Vbg)[i];
  {  // K: row-swizzled 16B chunks
    int chunk = d0 >> 3, off = d0 & 7;
    size_t kdst = ((size_t)h * KVL + kv) * 64 + (size_t)(((chunk ^ (kv & 7)) << 3) + off);
    ushort4 ok;
    ok.x = f2bf(ALPHA * kf.x); ok.y = f2bf(ALPHA * kf.y);
    ok.z = f2bf(ALPHA * kf.z); ok.w = f2bf(ALPHA * kf.w);
    *(ushort4*)(kb + kdst) = ok;
  }
  {  // V^T tiles: position-permuted + swizzled
    int tile = kv >> 6, kl = kv & 63;
    int c = vpos(kl);
    size_t vbase = ((size_t)h * 128 + tile) * 4096;
    float vv[4] = {vf.x, vf.y, vf.z, vf.w};
#pragma unroll
    for (int j = 0; j < 4; ++j) {
      int d = d0 + j;
      vbT[vbase + d * 64 + (((c >> 3) ^ (d & 7)) << 3) + (c & 7)] = f2bf(ALPHA * vv[j]);
    }
  }
}

// ---------------- fused QKV GEMM: z selects weight slice + epilogue ----------------
__global__ __launch_bounds__(512) void k_gemmQKV(
    const ushort* __restrict__ A, const ushort* __restrict__ WT,
    ushort* __restrict__ qb, ushort* __restrict__ kb, ushort* __restrict__ vbT) {
  __shared__ uint4 As4[128 * 8];
  __shared__ uint4 Bs4[64 * 8];
  int tid = threadIdx.x;
  int m0 = blockIdx.x * 128, n0 = blockIdx.y * 64;
  int z = blockIdx.z;
  const ushort* BT = WT + (size_t)z * CC * CC;
  int wid = tid >> 6, lane = tid & 63;
  int wr = wid >> 1, wc = wid & 1;
  int lr = lane & 15, lg = lane >> 4;
  f32x4 acc[2][2] = {};

  for (int kt = 0; kt < CC; kt += 64) {
    __syncthreads();
    {
      int id = tid;
#pragma unroll
      for (int i = 0; i < 2; ++i, id += 512) {
        int r = id >> 3, cc = id & 7;
        uint4 v = *(const uint4*)(A + (size_t)(m0 + r) * CC + kt + cc * 8);
        As4[r * 8 + (cc ^ (r & 7))] = v;
      }
      int r = tid >> 3, cc = tid & 7;
      uint4 v = *(const uint4*)(BT + (size_t)(n0 + r) * CC + kt + cc * 8);
      Bs4[r * 8 + (cc ^ (r & 7))] = v;
    }
    __syncthreads();
#pragma unroll
    for (int k0 = 0; k0 < 2; ++k0) {
      s16x8 a[2], b[2];
#pragma unroll
      for (int i = 0; i < 2; ++i) {
        int r = wr * 32 + i * 16 + lr;
        a[i] = *(const s16x8*)&As4[r * 8 + ((k0 * 4 + lg) ^ (r & 7))];
      }
#pragma unroll
      for (int j = 0; j < 2; ++j) {
        int r = wc * 32 + j * 16 + lr;
        b[j] = *(const s16x8*)&Bs4[r * 8 + ((k0 * 4 + lg) ^ (r & 7))];
      }
#pragma unroll
      for (int i = 0; i < 2; ++i)
#pragma unroll
        for (int j = 0; j < 2; ++j)
          acc[i][j] = __builtin_amdgcn_mfma_f32_16x16x32_bf16(a[i], b[j], acc[i][j], 0, 0, 0);
    }
  }
#pragma unroll
  for (int i = 0; i < 2; ++i)
#pragma unroll
    for (int j = 0; j < 2; ++j)
#pragma unroll
      for (int q = 0; q < 4; ++q) {
        int m = m0 + wr * 32 + i * 16 + lg * 4 + q;
        int n = n0 + wc * 32 + j * 16 + lr;
        float v = acc[i][j][q];
        if (z == 0) {        // Q: head layout, scaled by SC2
          qb[(size_t)(n >> 6) * ((size_t)LL * DD) + (size_t)m * 64 + (n & 63)] = f2bf(v * SC2);
        } else if (z == 1) { // K: row-swizzled
          int d = n & 63;
          kb[(size_t)(n >> 6) * ((size_t)KVL * DD) + (size_t)m * 64 +
             (((d >> 3) ^ (m & 7)) << 3) + (d & 7)] = f2bf(v);
        } else {             // V: V^T permuted tiles
          int d = n & 63, tile = m >> 6, kl = m & 63;
          int c = vpos(kl);
          vbT[((size_t)(n >> 6) * 128 + tile) * 4096 + (size_t)d * 64 +
              (((c >> 3) ^ (d & 7)) << 3) + (c & 7)] = f2bf(v);
        }
      }
}

// ---------------- final GEMM: fp32 + bias ----------------
__global__ __launch_bounds__(512) void k_gemmO(
    const ushort* __restrict__ A, const ushort* __restrict__ BT,
    float* __restrict__ outF, const float* __restrict__ bias) {
  __shared__ uint4 As4[128 * 8];
  __shared__ uint4 Bs4[64 * 8];
  int tid = threadIdx.x;
  int m0 = blockIdx.x * 128, n0 = blockIdx.y * 64;
  int wid = tid >> 6, lane = tid & 63;
  int wr = wid >> 1, wc = wid & 1;
  int lr = lane & 15, lg = lane >> 4;
  f32x4 acc[2][2] = {};

  for (int kt = 0; kt < CC; kt += 64) {
    __syncthreads();
    {
      int id = tid;
#pragma unroll
      for (int i = 0; i < 2; ++i, id += 512) {
        int r = id >> 3, cc = id & 7;
        uint4 v = *(const uint4*)(A + (size_t)(m0 + r) * CC + kt + cc * 8);
        As4[r * 8 + (cc ^ (r & 7))] = v;
      }
      int r = tid >> 3, cc = tid & 7;
      uint4 v = *(const uint4*)(BT + (size_t)(n0 + r) * CC + kt + cc * 8);
      Bs4[r * 8 + (cc ^ (r & 7))] = v;
    }
    __syncthreads();
#pragma unroll
    for (int k0 = 0; k0 < 2; ++k0) {
      s16x8 a[2], b[2];
#pragma unroll
      for (int i = 0; i < 2; ++i) {
        int r = wr * 32 + i * 16 + lr;
        a[i] = *(const s16x8*)&As4[r * 8 + ((k0 * 4 + lg) ^ (r & 7))];
      }
#pragma unroll
      for (int j = 0; j < 2; ++j) {
        int r = wc * 32 + j * 16 + lr;
        b[j] = *(const s16x8*)&Bs4[r * 8 + ((k0 * 4 + lg) ^ (r & 7))];
      }
#pragma unroll
      for (int i = 0; i < 2; ++i)
#pragma unroll
        for (int j = 0; j < 2; ++j)
          acc[i][j] = __builtin_amdgcn_mfma_f32_16x16x32_bf16(a[i], b[j], acc[i][j], 0, 0, 0);
    }
  }
#pragma unroll
  for (int i = 0; i < 2; ++i)
#pragma unroll
    for (int j = 0; j < 2; ++j)
#pragma unroll
      for (int q = 0; q < 4; ++q) {
        int m = m0 + wr * 32 + i * 16 + lg * 4 + q;
        int n = n0 + wc * 32 + j * 16 + lr;
        outF[(size_t)m * CC + n] = acc[i][j][q] + bias[n];
      }
}

// ---------------- flash attention (KV-split, static max, in-register P) ----------------
// R15-proven supertile schedule; partials now stored as bf16 (safe: rowsum
// L ~ 1e4 vs per-split |Op| ~ 1e2 -> normalized error ~1e-4).
__global__ __launch_bounds__(256, 2) void k_attn(
    const ushort* __restrict__ qb,    // [H][L][64], pre-scaled by SC2
    const ushort* __restrict__ kb,    // [H][KVL][64] row-swizzled
    const ushort* __restrict__ vbT,   // [H][128][4096] V^T permuted tiles
    ushort* __restrict__ Op,          // [nsp][H][L][64] unnormalized bf16
    float* __restrict__ lb,           // [nsp][H][L] row sums
    int nsp, int NT) {                // split count, SUPERTILES per split
  __shared__ ushort Ks[2][8192];
  __shared__ ushort Vs[2][8192];

  int tid = threadIdx.x, wid = tid >> 6, lane = tid & 63;
  int lr = lane & 15, lg = lane >> 4;

  // XCD-contiguous remap: dispatch round-robins flat%8 across XCDs; give each
  // XCD a contiguous logical span (16 qblk x (10*nsp/8) (h,sp) pairs).
  int flat = blockIdx.x;
  int span = 20 * nsp;               // grid/8
  int f2 = (flat & 7) * span + (flat >> 3);
  int qblk = f2 & 15;
  int hs = f2 >> 4;                  // 0..10*nsp-1
  int h = hs % HH;
  int sp = hs / HH;
  int q0 = qblk * 256 + wid * 64;

  // Q fragments: 4 row-blocks x 2 k-chunks (B-operand: lane -> Q[row=lr][d=lg*8..])
  s16x8 qa[4][2];
#pragma unroll
  for (int i = 0; i < 4; ++i) {
    const ushort* qptr = qb + ((size_t)h * LL + q0 + i * 16 + lr) * DD + lg * 8;
    qa[i][0] = *(const s16x8*)qptr;
    qa[i][1] = *(const s16x8*)(qptr + 32);
  }

  // ones B-fragment for rowsum MFMA
  s16x8 ones;
#pragma unroll
  for (int i = 0; i < 8; ++i) ones[i] = (short)0x3F80;

  f32x4 o[4][4] = {};
  f32x4 ol[4] = {};

  const ushort* kh = kb + (size_t)h * KVL * DD + (size_t)sp * NT * 8192;
  const ushort* vh = vbT + (size_t)h * 128 * 4096 + (size_t)sp * NT * 8192;

  // proven 64-kv body (pure function of the two LDS half-tile pointers)
  auto body = [&](const ushort* Kc, const ushort* Vc) {
    // S^T = K Q^T : 32 MFMA. Each K fragment feeds 4 row-block chains.
    f32x4 s[4][4] = {};
    __builtin_amdgcn_s_setprio(1);
#pragma unroll
    for (int k0 = 0; k0 < 2; ++k0) {
#pragma unroll
      for (int j = 0; j < 4; ++j) {
        int r = j * 16 + lr;
        s16x8 kf = *(const s16x8*)&Kc[r * 64 + (((k0 * 4 + lg) ^ (r & 7)) << 3)];
#pragma unroll
        for (int i = 0; i < 4; ++i)
          s[i][j] = __builtin_amdgcn_mfma_f32_16x16x32_bf16(kf, qa[i][k0], s[i][j], 0, 0, 0);
      }
    }
    __builtin_amdgcn_s_setprio(0);

    // P = exp2(S) (Q pre-scaled, static max), pack to bf16 pairs in-register
    uint w[4][4][2];
#pragma unroll
    for (int i = 0; i < 4; ++i)
#pragma unroll
      for (int j = 0; j < 4; ++j) {
        float p0 = fexp2(s[i][j][0]);
        float p1 = fexp2(s[i][j][1]);
        float p2 = fexp2(s[i][j][2]);
        float p3 = fexp2(s[i][j][3]);
        w[i][j][0] = cvtpk(p0, p1);
        w[i][j][1] = cvtpk(p2, p3);
      }

    // O += P V (32 MFMA) and rowsum l += P·1 (8 MFMA); V frag reused 4x
    __builtin_amdgcn_s_setprio(1);
#pragma unroll
    for (int k0 = 0; k0 < 2; ++k0) {
      s16x8 pa[4];
#pragma unroll
      for (int i = 0; i < 4; ++i) {
        uint4 u;
        u.x = w[i][2 * k0][0]; u.y = w[i][2 * k0][1];
        u.z = w[i][2 * k0 + 1][0]; u.w = w[i][2 * k0 + 1][1];
        pa[i] = __builtin_bit_cast(s16x8, u);
        ol[i] = __builtin_amdgcn_mfma_f32_16x16x32_bf16(pa[i], ones, ol[i], 0, 0, 0);
      }
#pragma unroll
      for (int j = 0; j < 4; ++j) {
        int r = j * 16 + lr;  // d row in V^T
        s16x8 bv = *(const s16x8*)&Vc[r * 64 + (((k0 * 4 + lg) ^ (r & 7)) << 3)];
#pragma unroll
        for (int i = 0; i < 4; ++i)
          o[i][j] = __builtin_amdgcn_mfma_f32_16x16x32_bf16(pa[i], bv, o[i][j], 0, 0, 0);
      }
    }
    __builtin_amdgcn_s_setprio(0);
  };

  // prologue: stage supertile 0 (4 K + 4 V gl16 per thread), wait, sync
#pragma unroll
  for (int i = 0; i < 4; ++i) {
    gl16(kh + (i * 256 + tid) * 8, &Ks[0][i * 2048 + wid * 512]);
    gl16(vh + (i * 256 + tid) * 8, &Vs[0][i * 2048 + wid * 512]);
  }
  asm volatile("s_waitcnt vmcnt(0)" ::: "memory");
  bar();

  for (int t = 0; t < NT; ++t) {
    if (t < NT - 1) {
      int nb = (t + 1) & 1;
      const ushort* gk = kh + (size_t)(t + 1) * 8192;
      const ushort* gv = vh + (size_t)(t + 1) * 8192;
#pragma unroll
      for (int i = 0; i < 4; ++i) {
        gl16(gk + (i * 256 + tid) * 8, &Ks[nb][i * 2048 + wid * 512]);
        gl16(gv + (i * 256 + tid) * 8, &Vs[nb][i * 2048 + wid * 512]);
      }
    }

    const ushort* Kc = Ks[t & 1];
    const ushort* Vc = Vs[t & 1];

    body(Kc, Vc);                    // kv half 0 (rows 0..63 of supertile)
    body(Kc + 4096, Vc + 4096);      // kv half 1 (rows 64..127)

    asm volatile("s_waitcnt vmcnt(0)" ::: "memory");  // next supertile landed
    bar();
  }

  // store unnormalized bf16 partials: row = q0 + i*16 + lg*4 + q, col = j*16 + lr
  size_t rbase = ((size_t)sp * HH + h) * LL;
#pragma unroll
  for (int i = 0; i < 4; ++i)
#pragma unroll
    for (int j = 0; j < 4; ++j)
#pragma unroll
      for (int q = 0; q < 4; ++q) {
        int row = q0 + i * 16 + lg * 4 + q;
        Op[(rbase + row) * 64 + j * 16 + lr] = f2bf(o[i][j][q]);
      }
  // rowsum: ol[i][q] identical across the 16 lr lanes; row = q0+i*16+lg*4+q
  if (lr == 0) {
#pragma unroll
    for (int i = 0; i < 4; ++i)
#pragma unroll
      for (int q = 0; q < 4; ++q)
        lb[rbase + q0 + i * 16 + lg * 4 + q] = ol[i][q];
  }
}

// ---------------- combine bf16 partials -> ctx bf16 [L][C] ----------------
__global__ __launch_bounds__(256) void k_comb(
    const ushort* __restrict__ Op, const float* __restrict__ lb,
    ushort* __restrict__ ctx, int nsp) {
  int t = threadIdx.x;
  int h = blockIdx.y;
  int row = blockIdx.x * 64 + (t >> 2);
  int d0 = (t & 3) * 16;

  float Lsum = 0.f;
  for (int s = 0; s < nsp; ++s)
    Lsum += lb[((size_t)s * HH + h) * LL + row];
  float inv = 1.0f / Lsum;

  float acc[16] = {};
  for (int s = 0; s < nsp; ++s) {
    size_t rb = (((size_t)s * HH + h) * LL + row) * 64 + d0;
    ushort tmp[16];
    *(uint4*)(tmp + 0) = *(const uint4*)(Op + rb + 0);
    *(uint4*)(tmp + 8) = *(const uint4*)(Op + rb + 8);
#pragma unroll
    for (int i = 0; i < 16; ++i) acc[i] += bf2f(tmp[i]);
  }
  ushort ob[16];
#pragma unroll
  for (int i = 0; i < 16; ++i) ob[i] = f2bf(acc[i] * inv);
  ushort* dst = ctx + (size_t)row * CC + h * 64 + d0;
  *(uint4*)(dst + 0) = *(uint4*)(ob + 0);
  *(uint4*)(dst + 8) = *(uint4*)(ob + 8);
}

extern "C" void kernel_launch(void* const* d_in, const int* in_sizes, int n_in,
                              void* d_out, int out_size, void* d_ws, size_t ws_size,
                              hipStream_t stream) {
  const float* hs  = (const float*)d_in[0];
  const float* Kbg = (const float*)d_in[1];
  const float* Vbg = (const float*)d_in[2];
  const float* Wq  = (const float*)d_in[3];
  const float* Wk  = (const float*)d_in[4];
  const float* Wv  = (const float*)d_in[5];
  const float* Wo  = (const float*)d_in[6];
  const float* bo  = (const float*)d_in[7];
  float* out = (float*)d_out;

  // fixed-layout scratch
  char* p = (char*)d_ws;
  ushort* hs_b = (ushort*)p; p += (size_t)LL * CC * 2;
  ushort* WqT  = (ushort*)p; p += (size_t)CC * CC * 2;   // WqT..WoT contiguous
  ushort* WkT  = (ushort*)p; p += (size_t)CC * CC * 2;
  ushort* WvT  = (ushort*)p; p += (size_t)CC * CC * 2;
  ushort* WoT  = (ushort*)p; p += (size_t)CC * CC * 2;
  ushort* qb   = (ushort*)p; p += (size_t)HH * LL * DD * 2;
  ushort* kb   = (ushort*)p; p += (size_t)HH * KVL * DD * 2;
  ushort* vbT  = (ushort*)p; p += (size_t)HH * KVL * DD * 2;
  ushort* ctxb = (ushort*)p; p += (size_t)LL * CC * 2;
  size_t fixedBytes = (size_t)(p - (char*)d_ws);
  (void)WkT; (void)WvT;

  // choose split by available workspace (deterministic in ws_size)
  int nsp = 16;
  {
    size_t need16 = fixedBytes + (size_t)16 * HH * LL * DD * 2 + (size_t)16 * HH * LL * 4;
    if (ws_size < need16) nsp = 8;
  }
  ushort* Opart = (ushort*)p; p += (size_t)nsp * HH * LL * DD * 2;
  float* lbuf   = (float*)p;  p += (size_t)nsp * HH * LL * 4;
  int NT = KVL / nsp / 128;  // supertiles (128 kv each) per split

  int n4hs = LL * CC / 4;
  k_cvt_hs<<<(n4hs + 255) / 256, 256, 0, stream>>>(hs, hs_b, n4hs);
  k_wT4<<<dim3(CC / 64, CC / 64, 4), 256, 0, stream>>>(Wq, Wk, Wv, Wo, WqT);
  int n4bg = HH * LL * DD / 4;
  k_cvt_bg<<<(n4bg + 255) / 256, 256, 0, stream>>>(Kbg, Vbg, kb, vbT, n4bg);

  k_gemmQKV<<<dim3(LL / 128, CC / 64, 3), 512, 0, stream>>>(hs_b, WqT, qb, kb, vbT);

  k_attn<<<dim3(16 * HH * nsp), 256, 0, stream>>>(qb, kb, vbT, Opart, lbuf, nsp, NT);
  k_comb<<<dim3(LL / 64, HH), 256, 0, stream>>>(Opart, lbuf, ctxb, nsp);

  k_gemmO<<<dim3(LL / 128, CC / 64), 512, 0, stream>>>(ctxb, WoT, out, bo);
}

// Round 17
// 144.782 us; speedup vs baseline: 1.0795x; 1.0795x over previous
//
#include <hip/hip_runtime.h>
#include <stdint.h>

#define HH 10
#define DD 64
#define LL 4096
#define CC 640
#define KVL 8192
#define ALPHA 0.42f
#define SC2 0.1803368801111204f  // (1/sqrt(64)) * log2(e)

typedef __attribute__((ext_vector_type(8))) short s16x8;
typedef __attribute__((ext_vector_type(4))) float f32x4;

__device__ inline ushort f2bf(float f) {
  uint32_t u = __builtin_bit_cast(uint32_t, f);
  u += 0x7FFFu + ((u >> 16) & 1u);   // RNE
  return (ushort)(u >> 16);
}

__device__ inline float bf2f(ushort u) {
  uint32_t x = (uint32_t)u << 16;
  return __builtin_bit_cast(float, x);
}

__device__ inline uint cvtpk(float lo, float hi) {
  uint r;
  asm("v_cvt_pk_bf16_f32 %0, %1, %2" : "=v"(r) : "v"(lo), "v"(hi));
  return r;
}

__device__ inline float fexp2(float x) {
  float r;
  asm("v_exp_f32 %0, %1" : "=v"(r) : "v"(x));  // pure, schedulable
  return r;
}

__device__ inline void gl16(const ushort* g, ushort* l) {
  __builtin_amdgcn_global_load_lds(
      (const __attribute__((address_space(1))) uint32_t*)g,
      (__attribute__((address_space(3))) uint32_t*)l, 16, 0, 0);
}

__device__ inline void bar() {
  __builtin_amdgcn_sched_barrier(0);
  __builtin_amdgcn_s_barrier();
  __builtin_amdgcn_sched_barrier(0);
}

// V^T tile column position for kv-local row kl (0..63), matching the
// register layout of the swapped-QK^T P fragment (see k_attn):
// A-slot s=8*lg+m (within 32-block k0) must hold kv = 32*k0+16*(m>>2)+4*lg+(m&3).
// Inverse: p = (kl&32) | ((kl&12)<<1) | ((kl&16)>>2) | (kl&3)
__device__ inline int vpos(int kl) {
  return (kl & 32) | ((kl & 12) << 1) | ((kl & 16) >> 2) | (kl & 3);
}

// ---------------- prep: hs fp32 -> bf16 ----------------
__global__ void k_cvt_hs(const float* __restrict__ in, ushort* __restrict__ out, int n4) {
  int i = blockIdx.x * blockDim.x + threadIdx.x;
  if (i < n4) {
    float4 v = ((const float4*)in)[i];
    ushort4 o;
    o.x = f2bf(v.x); o.y = f2bf(v.y); o.z = f2bf(v.z); o.w = f2bf(v.w);
    ((ushort4*)out)[i] = o;
  }
}

// ---------------- prep: 4x W [K][N] fp32 -> WT [N][K] bf16 (z-batched) ----------------
__global__ void k_wT4(const float* __restrict__ W0, const float* __restrict__ W1,
                      const float* __restrict__ W2, const float* __restrict__ W3,
                      ushort* __restrict__ WT) {
  __shared__ ushort t[64][65];
  const float* W = blockIdx.z == 0 ? W0 : blockIdx.z == 1 ? W1 : blockIdx.z == 2 ? W2 : W3;
  ushort* dst = WT + (size_t)blockIdx.z * CC * CC;
  int k0 = blockIdx.x * 64, n0 = blockIdx.y * 64;
  int tid = threadIdx.x;
#pragma unroll
  for (int i = 0; i < 4; ++i) {
    int id = tid + i * 256;
    int r = id >> 4, c4 = id & 15;
    float4 v = *(const float4*)(W + (size_t)(k0 + r) * CC + n0 + c4 * 4);
    t[r][c4 * 4 + 0] = f2bf(v.x);
    t[r][c4 * 4 + 1] = f2bf(v.y);
    t[r][c4 * 4 + 2] = f2bf(v.z);
    t[r][c4 * 4 + 3] = f2bf(v.w);
  }
  __syncthreads();
#pragma unroll
  for (int i = 0; i < 2; ++i) {
    int id = tid + i * 256;
    int n = id >> 3, cc = id & 7;
    ushort tmp[8];
#pragma unroll
    for (int j = 0; j < 8; ++j) tmp[j] = t[cc * 8 + j][n];
    *(uint4*)(dst + (size_t)(n0 + n) * CC + k0 + cc * 8) = *(uint4*)tmp;
  }
}

// ---------------- prep: background KV (rows L..KVL-1) ----------------
__global__ void k_cvt_bg(const float* __restrict__ Kbg, const float* __restrict__ Vbg,
                         ushort* __restrict__ kb, ushort* __restrict__ vbT, int n4) {
  int i = blockIdx.x * blockDim.x + threadIdx.x;
  if (i >= n4) return;
  int e = i * 4;
  int h = e / (LL * DD);
  int rem = e - h * (LL * DD);
  int kvl = rem >> 6;        // local row 0..4095
  int d0 = rem & 63;         // multiple of 4
  int kv = LL + kvl;         // global kv row
  float4 kf = ((const float4*)Kbg)[i];
  float4 vf = ((const float4*)Vbg)[i];
  {  // K: row-swizzled 16B chunks
    int chunk = d0 >> 3, off = d0 & 7;
    size_t kdst = ((size_t)h * KVL + kv) * 64 + (size_t)(((chunk ^ (kv & 7)) << 3) + off);
    ushort4 ok;
    ok.x = f2bf(ALPHA * kf.x); ok.y = f2bf(ALPHA * kf.y);
    ok.z = f2bf(ALPHA * kf.z); ok.w = f2bf(ALPHA * kf.w);
    *(ushort4*)(kb + kdst) = ok;
  }
  {  // V^T tiles: position-permuted + swizzled
    int tile = kv >> 6, kl = kv & 63;
    int c = vpos(kl);
    size_t vbase = ((size_t)h * 128 + tile) * 4096;
    float vv[4] = {vf.x, vf.y, vf.z, vf.w};
#pragma unroll
    for (int j = 0; j < 4; ++j) {
      int d = d0 + j;
      vbT[vbase + d * 64 + (((c >> 3) ^ (d & 7)) << 3) + (c & 7)] = f2bf(ALPHA * vv[j]);
    }
  }
}

// ---------------- fused QKV GEMM: z selects weight slice + epilogue ----------------
__global__ __launch_bounds__(512) void k_gemmQKV(
    const ushort* __restrict__ A, const ushort* __restrict__ WT,
    ushort* __restrict__ qb, ushort* __restrict__ kb, ushort* __restrict__ vbT) {
  __shared__ uint4 As4[128 * 8];
  __shared__ uint4 Bs4[64 * 8];
  int tid = threadIdx.x;
  int m0 = blockIdx.x * 128, n0 = blockIdx.y * 64;
  int z = blockIdx.z;
  const ushort* BT = WT + (size_t)z * CC * CC;
  int wid = tid >> 6, lane = tid & 63;
  int wr = wid >> 1, wc = wid & 1;
  int lr = lane & 15, lg = lane >> 4;
  f32x4 acc[2][2] = {};

  for (int kt = 0; kt < CC; kt += 64) {
    __syncthreads();
    {
      int id = tid;
#pragma unroll
      for (int i = 0; i < 2; ++i, id += 512) {
        int r = id >> 3, cc = id & 7;
        uint4 v = *(const uint4*)(A + (size_t)(m0 + r) * CC + kt + cc * 8);
        As4[r * 8 + (cc ^ (r & 7))] = v;
      }
      int r = tid >> 3, cc = tid & 7;
      uint4 v = *(const uint4*)(BT + (size_t)(n0 + r) * CC + kt + cc * 8);
      Bs4[r * 8 + (cc ^ (r & 7))] = v;
    }
    __syncthreads();
#pragma unroll
    for (int k0 = 0; k0 < 2; ++k0) {
      s16x8 a[2], b[2];
#pragma unroll
      for (int i = 0; i < 2; ++i) {
        int r = wr * 32 + i * 16 + lr;
        a[i] = *(const s16x8*)&As4[r * 8 + ((k0 * 4 + lg) ^ (r & 7))];
      }
#pragma unroll
      for (int j = 0; j < 2; ++j) {
        int r = wc * 32 + j * 16 + lr;
        b[j] = *(const s16x8*)&Bs4[r * 8 + ((k0 * 4 + lg) ^ (r & 7))];
      }
#pragma unroll
      for (int i = 0; i < 2; ++i)
#pragma unroll
        for (int j = 0; j < 2; ++j)
          acc[i][j] = __builtin_amdgcn_mfma_f32_16x16x32_bf16(a[i], b[j], acc[i][j], 0, 0, 0);
    }
  }
#pragma unroll
  for (int i = 0; i < 2; ++i)
#pragma unroll
    for (int j = 0; j < 2; ++j)
#pragma unroll
      for (int q = 0; q < 4; ++q) {
        int m = m0 + wr * 32 + i * 16 + lg * 4 + q;
        int n = n0 + wc * 32 + j * 16 + lr;
        float v = acc[i][j][q];
        if (z == 0) {        // Q: head layout, scaled by SC2
          qb[(size_t)(n >> 6) * ((size_t)LL * DD) + (size_t)m * 64 + (n & 63)] = f2bf(v * SC2);
        } else if (z == 1) { // K: row-swizzled
          int d = n & 63;
          kb[(size_t)(n >> 6) * ((size_t)KVL * DD) + (size_t)m * 64 +
             (((d >> 3) ^ (m & 7)) << 3) + (d & 7)] = f2bf(v);
        } else {             // V: V^T permuted tiles
          int d = n & 63, tile = m >> 6, kl = m & 63;
          int c = vpos(kl);
          vbT[((size_t)(n >> 6) * 128 + tile) * 4096 + (size_t)d * 64 +
              (((c >> 3) ^ (d & 7)) << 3) + (c & 7)] = f2bf(v);
        }
      }
}

// ---------------- final GEMM: fp32 + bias ----------------
__global__ __launch_bounds__(512) void k_gemmO(
    const ushort* __restrict__ A, const ushort* __restrict__ BT,
    float* __restrict__ outF, const float* __restrict__ bias) {
  __shared__ uint4 As4[128 * 8];
  __shared__ uint4 Bs4[64 * 8];
  int tid = threadIdx.x;
  int m0 = blockIdx.x * 128, n0 = blockIdx.y * 64;
  int wid = tid >> 6, lane = tid & 63;
  int wr = wid >> 1, wc = wid & 1;
  int lr = lane & 15, lg = lane >> 4;
  f32x4 acc[2][2] = {};

  for (int kt = 0; kt < CC; kt += 64) {
    __syncthreads();
    {
      int id = tid;
#pragma unroll
      for (int i = 0; i < 2; ++i, id += 512) {
        int r = id >> 3, cc = id & 7;
        uint4 v = *(const uint4*)(A + (size_t)(m0 + r) * CC + kt + cc * 8);
        As4[r * 8 + (cc ^ (r & 7))] = v;
      }
      int r = tid >> 3, cc = tid & 7;
      uint4 v = *(const uint4*)(BT + (size_t)(n0 + r) * CC + kt + cc * 8);
      Bs4[r * 8 + (cc ^ (r & 7))] = v;
    }
    __syncthreads();
#pragma unroll
    for (int k0 = 0; k0 < 2; ++k0) {
      s16x8 a[2], b[2];
#pragma unroll
      for (int i = 0; i < 2; ++i) {
        int r = wr * 32 + i * 16 + lr;
        a[i] = *(const s16x8*)&As4[r * 8 + ((k0 * 4 + lg) ^ (r & 7))];
      }
#pragma unroll
      for (int j = 0; j < 2; ++j) {
        int r = wc * 32 + j * 16 + lr;
        b[j] = *(const s16x8*)&Bs4[r * 8 + ((k0 * 4 + lg) ^ (r & 7))];
      }
#pragma unroll
      for (int i = 0; i < 2; ++i)
#pragma unroll
        for (int j = 0; j < 2; ++j)
          acc[i][j] = __builtin_amdgcn_mfma_f32_16x16x32_bf16(a[i], b[j], acc[i][j], 0, 0, 0);
    }
  }
#pragma unroll
  for (int i = 0; i < 2; ++i)
#pragma unroll
    for (int j = 0; j < 2; ++j)
#pragma unroll
      for (int q = 0; q < 4; ++q) {
        int m = m0 + wr * 32 + i * 16 + lg * 4 + q;
        int n = n0 + wc * 32 + j * 16 + lr;
        outF[(size_t)m * CC + n] = acc[i][j][q] + bias[n];
      }
}

// ---------------- flash attention (KV-split, static max, in-register P) ----------------
// R15-proven supertile schedule (nsp=8); partials stored as bf16 (validated
// in R16: absmax unchanged; rowsum L ~ 1e4 vs |Op| ~ 1e2 -> err ~1e-4).
__global__ __launch_bounds__(256, 2) void k_attn(
    const ushort* __restrict__ qb,    // [H][L][64], pre-scaled by SC2
    const ushort* __restrict__ kb,    // [H][KVL][64] row-swizzled
    const ushort* __restrict__ vbT,   // [H][128][4096] V^T permuted tiles
    ushort* __restrict__ Op,          // [nsp][H][L][64] unnormalized bf16
    float* __restrict__ lb,           // [nsp][H][L] row sums
    int nsp, int NT) {                // split count, SUPERTILES per split
  __shared__ ushort Ks[2][8192];
  __shared__ ushort Vs[2][8192];

  int tid = threadIdx.x, wid = tid >> 6, lane = tid & 63;
  int lr = lane & 15, lg = lane >> 4;

  // XCD-contiguous remap: dispatch round-robins flat%8 across XCDs; give each
  // XCD a contiguous logical span (16 qblk x (10*nsp/8) (h,sp) pairs).
  int flat = blockIdx.x;
  int span = 20 * nsp;               // grid/8
  int f2 = (flat & 7) * span + (flat >> 3);
  int qblk = f2 & 15;
  int hs = f2 >> 4;                  // 0..10*nsp-1
  int h = hs % HH;
  int sp = hs / HH;
  int q0 = qblk * 256 + wid * 64;

  // Q fragments: 4 row-blocks x 2 k-chunks (B-operand: lane -> Q[row=lr][d=lg*8..])
  s16x8 qa[4][2];
#pragma unroll
  for (int i = 0; i < 4; ++i) {
    const ushort* qptr = qb + ((size_t)h * LL + q0 + i * 16 + lr) * DD + lg * 8;
    qa[i][0] = *(const s16x8*)qptr;
    qa[i][1] = *(const s16x8*)(qptr + 32);
  }

  // ones B-fragment for rowsum MFMA
  s16x8 ones;
#pragma unroll
  for (int i = 0; i < 8; ++i) ones[i] = (short)0x3F80;

  f32x4 o[4][4] = {};
  f32x4 ol[4] = {};

  const ushort* kh = kb + (size_t)h * KVL * DD + (size_t)sp * NT * 8192;
  const ushort* vh = vbT + (size_t)h * 128 * 4096 + (size_t)sp * NT * 8192;

  // proven 64-kv body (pure function of the two LDS half-tile pointers)
  auto body = [&](const ushort* Kc, const ushort* Vc) {
    // S^T = K Q^T : 32 MFMA. Each K fragment feeds 4 row-block chains.
    f32x4 s[4][4] = {};
    __builtin_amdgcn_s_setprio(1);
#pragma unroll
    for (int k0 = 0; k0 < 2; ++k0) {
#pragma unroll
      for (int j = 0; j < 4; ++j) {
        int r = j * 16 + lr;
        s16x8 kf = *(const s16x8*)&Kc[r * 64 + (((k0 * 4 + lg) ^ (r & 7)) << 3)];
#pragma unroll
        for (int i = 0; i < 4; ++i)
          s[i][j] = __builtin_amdgcn_mfma_f32_16x16x32_bf16(kf, qa[i][k0], s[i][j], 0, 0, 0);
      }
    }
    __builtin_amdgcn_s_setprio(0);

    // P = exp2(S) (Q pre-scaled, static max), pack to bf16 pairs in-register
    uint w[4][4][2];
#pragma unroll
    for (int i = 0; i < 4; ++i)
#pragma unroll
      for (int j = 0; j < 4; ++j) {
        float p0 = fexp2(s[i][j][0]);
        float p1 = fexp2(s[i][j][1]);
        float p2 = fexp2(s[i][j][2]);
        float p3 = fexp2(s[i][j][3]);
        w[i][j][0] = cvtpk(p0, p1);
        w[i][j][1] = cvtpk(p2, p3);
      }

    // O += P V (32 MFMA) and rowsum l += P·1 (8 MFMA); V frag reused 4x
    __builtin_amdgcn_s_setprio(1);
#pragma unroll
    for (int k0 = 0; k0 < 2; ++k0) {
      s16x8 pa[4];
#pragma unroll
      for (int i = 0; i < 4; ++i) {
        uint4 u;
        u.x = w[i][2 * k0][0]; u.y = w[i][2 * k0][1];
        u.z = w[i][2 * k0 + 1][0]; u.w = w[i][2 * k0 + 1][1];
        pa[i] = __builtin_bit_cast(s16x8, u);
        ol[i] = __builtin_amdgcn_mfma_f32_16x16x32_bf16(pa[i], ones, ol[i], 0, 0, 0);
      }
#pragma unroll
      for (int j = 0; j < 4; ++j) {
        int r = j * 16 + lr;  // d row in V^T
        s16x8 bv = *(const s16x8*)&Vc[r * 64 + (((k0 * 4 + lg) ^ (r & 7)) << 3)];
#pragma unroll
        for (int i = 0; i < 4; ++i)
          o[i][j] = __builtin_amdgcn_mfma_f32_16x16x32_bf16(pa[i], bv, o[i][j], 0, 0, 0);
      }
    }
    __builtin_amdgcn_s_setprio(0);
  };

  // prologue: stage supertile 0 (4 K + 4 V gl16 per thread), wait, sync
#pragma unroll
  for (int i = 0; i < 4; ++i) {
    gl16(kh + (i * 256 + tid) * 8, &Ks[0][i * 2048 + wid * 512]);
    gl16(vh + (i * 256 + tid) * 8, &Vs[0][i * 2048 + wid * 512]);
  }
  asm volatile("s_waitcnt vmcnt(0)" ::: "memory");
  bar();

  for (int t = 0; t < NT; ++t) {
    if (t < NT - 1) {
      int nb = (t + 1) & 1;
      const ushort* gk = kh + (size_t)(t + 1) * 8192;
      const ushort* gv = vh + (size_t)(t + 1) * 8192;
#pragma unroll
      for (int i = 0; i < 4; ++i) {
        gl16(gk + (i * 256 + tid) * 8, &Ks[nb][i * 2048 + wid * 512]);
        gl16(gv + (i * 256 + tid) * 8, &Vs[nb][i * 2048 + wid * 512]);
      }
    }

    const ushort* Kc = Ks[t & 1];
    const ushort* Vc = Vs[t & 1];

    body(Kc, Vc);                    // kv half 0 (rows 0..63 of supertile)
    body(Kc + 4096, Vc + 4096);      // kv half 1 (rows 64..127)

    asm volatile("s_waitcnt vmcnt(0)" ::: "memory");  // next supertile landed
    bar();
  }

  // store unnormalized bf16 partials: row = q0 + i*16 + lg*4 + q, col = j*16 + lr
  size_t rbase = ((size_t)sp * HH + h) * LL;
#pragma unroll
  for (int i = 0; i < 4; ++i)
#pragma unroll
    for (int j = 0; j < 4; ++j)
#pragma unroll
      for (int q = 0; q < 4; ++q) {
        int row = q0 + i * 16 + lg * 4 + q;
        Op[(rbase + row) * 64 + j * 16 + lr] = f2bf(o[i][j][q]);
      }
  // rowsum: ol[i][q] identical across the 16 lr lanes; row = q0+i*16+lg*4+q
  if (lr == 0) {
#pragma unroll
    for (int i = 0; i < 4; ++i)
#pragma unroll
      for (int q = 0; q < 4; ++q)
        lb[rbase + q0 + i * 16 + lg * 4 + q] = ol[i][q];
  }
}

// ---------------- combine bf16 partials -> ctx bf16 [L][C] ----------------
__global__ __launch_bounds__(256) void k_comb(
    const ushort* __restrict__ Op, const float* __restrict__ lb,
    ushort* __restrict__ ctx, int nsp) {
  int t = threadIdx.x;
  int h = blockIdx.y;
  int row = blockIdx.x * 64 + (t >> 2);
  int d0 = (t & 3) * 16;

  float Lsum = 0.f;
  for (int s = 0; s < nsp; ++s)
    Lsum += lb[((size_t)s * HH + h) * LL + row];
  float inv = 1.0f / Lsum;

  float acc[16] = {};
  for (int s = 0; s < nsp; ++s) {
    size_t rb = (((size_t)s * HH + h) * LL + row) * 64 + d0;
    ushort tmp[16];
    *(uint4*)(tmp + 0) = *(const uint4*)(Op + rb + 0);
    *(uint4*)(tmp + 8) = *(const uint4*)(Op + rb + 8);
#pragma unroll
    for (int i = 0; i < 16; ++i) acc[i] += bf2f(tmp[i]);
  }
  ushort ob[16];
#pragma unroll
  for (int i = 0; i < 16; ++i) ob[i] = f2bf(acc[i] * inv);
  ushort* dst = ctx + (size_t)row * CC + h * 64 + d0;
  *(uint4*)(dst + 0) = *(uint4*)(ob + 0);
  *(uint4*)(dst + 8) = *(uint4*)(ob + 8);
}

extern "C" void kernel_launch(void* const* d_in, const int* in_sizes, int n_in,
                              void* d_out, int out_size, void* d_ws, size_t ws_size,
                              hipStream_t stream) {
  const float* hs  = (const float*)d_in[0];
  const float* Kbg = (const float*)d_in[1];
  const float* Vbg = (const float*)d_in[2];
  const float* Wq  = (const float*)d_in[3];
  const float* Wk  = (const float*)d_in[4];
  const float* Wv  = (const float*)d_in[5];
  const float* Wo  = (const float*)d_in[6];
  const float* bo  = (const float*)d_in[7];
  float* out = (float*)d_out;

  // fixed-layout scratch
  char* p = (char*)d_ws;
  ushort* hs_b = (ushort*)p; p += (size_t)LL * CC * 2;
  ushort* WqT  = (ushort*)p; p += (size_t)CC * CC * 2;   // WqT..WoT contiguous
  ushort* WkT  = (ushort*)p; p += (size_t)CC * CC * 2;
  ushort* WvT  = (ushort*)p; p += (size_t)CC * CC * 2;
  ushort* WoT  = (ushort*)p; p += (size_t)CC * CC * 2;
  ushort* qb   = (ushort*)p; p += (size_t)HH * LL * DD * 2;
  ushort* kb   = (ushort*)p; p += (size_t)HH * KVL * DD * 2;
  ushort* vbT  = (ushort*)p; p += (size_t)HH * KVL * DD * 2;
  ushort* ctxb = (ushort*)p; p += (size_t)LL * CC * 2;
  (void)WkT; (void)WvT;

  int nsp = 8;
  ushort* Opart = (ushort*)p; p += (size_t)nsp * HH * LL * DD * 2;
  float* lbuf   = (float*)p;  p += (size_t)nsp * HH * LL * 4;
  int NT = KVL / nsp / 128;  // supertiles (128 kv each) per split

  int n4hs = LL * CC / 4;
  k_cvt_hs<<<(n4hs + 255) / 256, 256, 0, stream>>>(hs, hs_b, n4hs);
  k_wT4<<<dim3(CC / 64, CC / 64, 4), 256, 0, stream>>>(Wq, Wk, Wv, Wo, WqT);
  int n4bg = HH * LL * DD / 4;
  k_cvt_bg<<<(n4bg + 255) / 256, 256, 0, stream>>>(Kbg, Vbg, kb, vbT, n4bg);

  k_gemmQKV<<<dim3(LL / 128, CC / 64, 3), 512, 0, stream>>>(hs_b, WqT, qb, kb, vbT);

  k_attn<<<dim3(16 * HH * nsp), 256, 0, stream>>>(qb, kb, vbT, Opart, lbuf, nsp, NT);
  k_comb<<<dim3(LL / 64, HH), 256, 0, stream>>>(Opart, lbuf, ctxb, nsp);

  k_gemmO<<<dim3(LL / 128, CC / 64), 512, 0, stream>>>(ctxb, WoT, out, bo);
}

// Round 18
// 142.617 us; speedup vs baseline: 1.0959x; 1.0152x over previous
//
#include <hip/hip_runtime.h>
#include <stdint.h>

#define HH 10
#define DD 64
#define LL 4096
#define CC 640
#define KVL 8192
#define ALPHA 0.42f
#define SC2 0.1803368801111204f  // (1/sqrt(64)) * log2(e)

typedef __attribute__((ext_vector_type(8))) short s16x8;
typedef __attribute__((ext_vector_type(4))) float f32x4;

__device__ inline ushort f2bf(float f) {
  uint32_t u = __builtin_bit_cast(uint32_t, f);
  u += 0x7FFFu + ((u >> 16) & 1u);   // RNE
  return (ushort)(u >> 16);
}

__device__ inline float bf2f(ushort u) {
  uint32_t x = (uint32_t)u << 16;
  return __builtin_bit_cast(float, x);
}

__device__ inline uint cvtpk(float lo, float hi) {
  uint r;
  asm("v_cvt_pk_bf16_f32 %0, %1, %2" : "=v"(r) : "v"(lo), "v"(hi));
  return r;
}

__device__ inline float fexp2(float x) {
  float r;
  asm("v_exp_f32 %0, %1" : "=v"(r) : "v"(x));  // pure, schedulable
  return r;
}

__device__ inline void gl16(const ushort* g, ushort* l) {
  __builtin_amdgcn_global_load_lds(
      (const __attribute__((address_space(1))) uint32_t*)g,
      (__attribute__((address_space(3))) uint32_t*)l, 16, 0, 0);
}

__device__ inline void bar() {
  __builtin_amdgcn_sched_barrier(0);
  __builtin_amdgcn_s_barrier();
  __builtin_amdgcn_sched_barrier(0);
}

// V^T tile column position for kv-local row kl (0..63), matching the
// register layout of the swapped-QK^T P fragment (see k_attn):
// A-slot s=8*lg+m (within 32-block k0) must hold kv = 32*k0+16*(m>>2)+4*lg+(m&3).
// Inverse: p = (kl&32) | ((kl&12)<<1) | ((kl&16)>>2) | (kl&3)
__device__ inline int vpos(int kl) {
  return (kl & 32) | ((kl & 12) << 1) | ((kl & 16) >> 2) | (kl & 3);
}
// bit-inverse of vpos (c5->kl5, c4->kl3, c3->kl2, c2->kl4, c1->kl1, c0->kl0)
__device__ inline int vposInv(int c) {
  return (c & 32) | ((c & 24) >> 1) | ((c & 4) << 2) | (c & 3);
}

// ---------------- prep: hs fp32 -> bf16 ----------------
__global__ void k_cvt_hs(const float* __restrict__ in, ushort* __restrict__ out, int n4) {
  int i = blockIdx.x * blockDim.x + threadIdx.x;
  if (i < n4) {
    float4 v = ((const float4*)in)[i];
    ushort4 o;
    o.x = f2bf(v.x); o.y = f2bf(v.y); o.z = f2bf(v.z); o.w = f2bf(v.w);
    ((ushort4*)out)[i] = o;
  }
}

// ---------------- prep: 4x W [K][N] fp32 -> WT [N][K] bf16 (z-batched) ----------------
__global__ void k_wT4(const float* __restrict__ W0, const float* __restrict__ W1,
                      const float* __restrict__ W2, const float* __restrict__ W3,
                      ushort* __restrict__ WT) {
  __shared__ ushort t[64][65];
  const float* W = blockIdx.z == 0 ? W0 : blockIdx.z == 1 ? W1 : blockIdx.z == 2 ? W2 : W3;
  ushort* dst = WT + (size_t)blockIdx.z * CC * CC;
  int k0 = blockIdx.x * 64, n0 = blockIdx.y * 64;
  int tid = threadIdx.x;
#pragma unroll
  for (int i = 0; i < 4; ++i) {
    int id = tid + i * 256;
    int r = id >> 4, c4 = id & 15;
    float4 v = *(const float4*)(W + (size_t)(k0 + r) * CC + n0 + c4 * 4);
    t[r][c4 * 4 + 0] = f2bf(v.x);
    t[r][c4 * 4 + 1] = f2bf(v.y);
    t[r][c4 * 4 + 2] = f2bf(v.z);
    t[r][c4 * 4 + 3] = f2bf(v.w);
  }
  __syncthreads();
#pragma unroll
  for (int i = 0; i < 2; ++i) {
    int id = tid + i * 256;
    int n = id >> 3, cc = id & 7;
    ushort tmp[8];
#pragma unroll
    for (int j = 0; j < 8; ++j) tmp[j] = t[cc * 8 + j][n];
    *(uint4*)(dst + (size_t)(n0 + n) * CC + k0 + cc * 8) = *(uint4*)tmp;
  }
}

// ---------------- prep: background K (rows L..KVL-1), row-swizzled ----------------
__global__ void k_cvt_bgK(const float* __restrict__ Kbg, ushort* __restrict__ kb, int n4) {
  int i = blockIdx.x * blockDim.x + threadIdx.x;
  if (i >= n4) return;
  int e = i * 4;
  int h = e / (LL * DD);
  int rem = e - h * (LL * DD);
  int kvl = rem >> 6;        // local row 0..4095
  int d0 = rem & 63;         // multiple of 4
  int kv = LL + kvl;         // global kv row
  float4 kf = ((const float4*)Kbg)[i];
  int chunk = d0 >> 3, off = d0 & 7;
  size_t kdst = ((size_t)h * KVL + kv) * 64 + (size_t)(((chunk ^ (kv & 7)) << 3) + off);
  ushort4 ok;
  ok.x = f2bf(ALPHA * kf.x); ok.y = f2bf(ALPHA * kf.y);
  ok.z = f2bf(ALPHA * kf.z); ok.w = f2bf(ALPHA * kf.w);
  *(ushort4*)(kb + kdst) = ok;
}

// ---------------- prep: background V -> V^T permuted tiles (coalesced LDS transpose) ----------------
// Same output contract as the old scatter path: for tile 64+tt of head h,
// vbT[(h*128+64+tt)*4096 + d*64 + sw(c,d)] = bf16(ALPHA * V[h][tt*64+kl][d]),
// c = vpos(kl), sw(c,d) = (((c>>3)^(d&7))<<3)|(c&7).
__global__ __launch_bounds__(256) void k_cvt_bgV(const float* __restrict__ Vbg,
                                                 ushort* __restrict__ vbT) {
  __shared__ ushort t[64][66];   // [kl][d], +2 pad vs bank conflicts
  int tt = blockIdx.x;           // bg tile 0..63 -> global tile 64+tt
  int h = blockIdx.y;
  int tid = threadIdx.x;
#pragma unroll
  for (int k = 0; k < 4; ++k) {
    int id = tid + k * 256;
    int r = id >> 4, c4 = id & 15;   // kl row r, d cols c4*4..c4*4+3
    float4 v = *(const float4*)(Vbg + ((size_t)h * LL + tt * 64 + r) * DD + c4 * 4);
    t[r][c4 * 4 + 0] = f2bf(ALPHA * v.x);
    t[r][c4 * 4 + 1] = f2bf(ALPHA * v.y);
    t[r][c4 * 4 + 2] = f2bf(ALPHA * v.z);
    t[r][c4 * 4 + 3] = f2bf(ALPHA * v.w);
  }
  __syncthreads();
  // write d-major, coalesced: thread covers d = tid>>2, positions (tid&3)*16..+15
  int d = tid >> 2;
  int p0 = (tid & 3) * 16;
  ushort tmp[16];
#pragma unroll
  for (int pp = 0; pp < 16; ++pp) {
    int pos = p0 + pp;
    int c = (((pos >> 3) ^ (d & 7)) << 3) | (pos & 7);  // sw is involutive per d
    tmp[pp] = t[vposInv(c)][d];
  }
  ushort* dst = vbT + ((size_t)h * 128 + 64 + tt) * 4096 + d * 64 + p0;
  *(uint4*)(dst + 0) = *(uint4*)(tmp + 0);
  *(uint4*)(dst + 8) = *(uint4*)(tmp + 8);
}

// ---------------- fused QKV GEMM: z selects weight slice + epilogue ----------------
__global__ __launch_bounds__(512) void k_gemmQKV(
    const ushort* __restrict__ A, const ushort* __restrict__ WT,
    ushort* __restrict__ qb, ushort* __restrict__ kb, ushort* __restrict__ vbT) {
  __shared__ uint4 As4[128 * 8];
  __shared__ uint4 Bs4[64 * 8];
  int tid = threadIdx.x;
  int m0 = blockIdx.x * 128, n0 = blockIdx.y * 64;
  int z = blockIdx.z;
  const ushort* BT = WT + (size_t)z * CC * CC;
  int wid = tid >> 6, lane = tid & 63;
  int wr = wid >> 1, wc = wid & 1;
  int lr = lane & 15, lg = lane >> 4;
  f32x4 acc[2][2] = {};

  for (int kt = 0; kt < CC; kt += 64) {
    __syncthreads();
    {
      int id = tid;
#pragma unroll
      for (int i = 0; i < 2; ++i, id += 512) {
        int r = id >> 3, cc = id & 7;
        uint4 v = *(const uint4*)(A + (size_t)(m0 + r) * CC + kt + cc * 8);
        As4[r * 8 + (cc ^ (r & 7))] = v;
      }
      int r = tid >> 3, cc = tid & 7;
      uint4 v = *(const uint4*)(BT + (size_t)(n0 + r) * CC + kt + cc * 8);
      Bs4[r * 8 + (cc ^ (r & 7))] = v;
    }
    __syncthreads();
#pragma unroll
    for (int k0 = 0; k0 < 2; ++k0) {
      s16x8 a[2], b[2];
#pragma unroll
      for (int i = 0; i < 2; ++i) {
        int r = wr * 32 + i * 16 + lr;
        a[i] = *(const s16x8*)&As4[r * 8 + ((k0 * 4 + lg) ^ (r & 7))];
      }
#pragma unroll
      for (int j = 0; j < 2; ++j) {
        int r = wc * 32 + j * 16 + lr;
        b[j] = *(const s16x8*)&Bs4[r * 8 + ((k0 * 4 + lg) ^ (r & 7))];
      }
#pragma unroll
      for (int i = 0; i < 2; ++i)
#pragma unroll
        for (int j = 0; j < 2; ++j)
          acc[i][j] = __builtin_amdgcn_mfma_f32_16x16x32_bf16(a[i], b[j], acc[i][j], 0, 0, 0);
    }
  }
#pragma unroll
  for (int i = 0; i < 2; ++i)
#pragma unroll
    for (int j = 0; j < 2; ++j)
#pragma unroll
      for (int q = 0; q < 4; ++q) {
        int m = m0 + wr * 32 + i * 16 + lg * 4 + q;
        int n = n0 + wc * 32 + j * 16 + lr;
        float v = acc[i][j][q];
        if (z == 0) {        // Q: head layout, scaled by SC2
          qb[(size_t)(n >> 6) * ((size_t)LL * DD) + (size_t)m * 64 + (n & 63)] = f2bf(v * SC2);
        } else if (z == 1) { // K: row-swizzled
          int d = n & 63;
          kb[(size_t)(n >> 6) * ((size_t)KVL * DD) + (size_t)m * 64 +
             (((d >> 3) ^ (m & 7)) << 3) + (d & 7)] = f2bf(v);
        } else {             // V: V^T permuted tiles
          int d = n & 63, tile = m >> 6, kl = m & 63;
          int c = vpos(kl);
          vbT[((size_t)(n >> 6) * 128 + tile) * 4096 + (size_t)d * 64 +
              (((c >> 3) ^ (d & 7)) << 3) + (c & 7)] = f2bf(v);
        }
      }
}

// ---------------- final GEMM: fp32 + bias ----------------
__global__ __launch_bounds__(512) void k_gemmO(
    const ushort* __restrict__ A, const ushort* __restrict__ BT,
    float* __restrict__ outF, const float* __restrict__ bias) {
  __shared__ uint4 As4[128 * 8];
  __shared__ uint4 Bs4[64 * 8];
  int tid = threadIdx.x;
  int m0 = blockIdx.x * 128, n0 = blockIdx.y * 64;
  int wid = tid >> 6, lane = tid & 63;
  int wr = wid >> 1, wc = wid & 1;
  int lr = lane & 15, lg = lane >> 4;
  f32x4 acc[2][2] = {};

  for (int kt = 0; kt < CC; kt += 64) {
    __syncthreads();
    {
      int id = tid;
#pragma unroll
      for (int i = 0; i < 2; ++i, id += 512) {
        int r = id >> 3, cc = id & 7;
        uint4 v = *(const uint4*)(A + (size_t)(m0 + r) * CC + kt + cc * 8);
        As4[r * 8 + (cc ^ (r & 7))] = v;
      }
      int r = tid >> 3, cc = tid & 7;
      uint4 v = *(const uint4*)(BT + (size_t)(n0 + r) * CC + kt + cc * 8);
      Bs4[r * 8 + (cc ^ (r & 7))] = v;
    }
    __syncthreads();
#pragma unroll
    for (int k0 = 0; k0 < 2; ++k0) {
      s16x8 a[2], b[2];
#pragma unroll
      for (int i = 0; i < 2; ++i) {
        int r = wr * 32 + i * 16 + lr;
        a[i] = *(const s16x8*)&As4[r * 8 + ((k0 * 4 + lg) ^ (r & 7))];
      }
#pragma unroll
      for (int j = 0; j < 2; ++j) {
        int r = wc * 32 + j * 16 + lr;
        b[j] = *(const s16x8*)&Bs4[r * 8 + ((k0 * 4 + lg) ^ (r & 7))];
      }
#pragma unroll
      for (int i = 0; i < 2; ++i)
#pragma unroll
        for (int j = 0; j < 2; ++j)
          acc[i][j] = __builtin_amdgcn_mfma_f32_16x16x32_bf16(a[i], b[j], acc[i][j], 0, 0, 0);
    }
  }
#pragma unroll
  for (int i = 0; i < 2; ++i)
#pragma unroll
    for (int j = 0; j < 2; ++j)
#pragma unroll
      for (int q = 0; q < 4; ++q) {
        int m = m0 + wr * 32 + i * 16 + lg * 4 + q;
        int n = n0 + wc * 32 + j * 16 + lr;
        outF[(size_t)m * CC + n] = acc[i][j][q] + bias[n];
      }
}

// ---------------- flash attention (KV-split, static max, in-register P) ----------------
// R15/R17-proven supertile schedule (nsp=8), bf16 partials.
__global__ __launch_bounds__(256, 2) void k_attn(
    const ushort* __restrict__ qb,    // [H][L][64], pre-scaled by SC2
    const ushort* __restrict__ kb,    // [H][KVL][64] row-swizzled
    const ushort* __restrict__ vbT,   // [H][128][4096] V^T permuted tiles
    ushort* __restrict__ Op,          // [nsp][H][L][64] unnormalized bf16
    float* __restrict__ lb,           // [nsp][H][L] row sums
    int nsp, int NT) {                // split count, SUPERTILES per split
  __shared__ ushort Ks[2][8192];
  __shared__ ushort Vs[2][8192];

  int tid = threadIdx.x, wid = tid >> 6, lane = tid & 63;
  int lr = lane & 15, lg = lane >> 4;

  // XCD-contiguous remap: dispatch round-robins flat%8 across XCDs; give each
  // XCD a contiguous logical span (16 qblk x (10*nsp/8) (h,sp) pairs).
  int flat = blockIdx.x;
  int span = 20 * nsp;               // grid/8
  int f2 = (flat & 7) * span + (flat >> 3);
  int qblk = f2 & 15;
  int hs = f2 >> 4;                  // 0..10*nsp-1
  int h = hs % HH;
  int sp = hs / HH;
  int q0 = qblk * 256 + wid * 64;

  // Q fragments: 4 row-blocks x 2 k-chunks (B-operand: lane -> Q[row=lr][d=lg*8..])
  s16x8 qa[4][2];
#pragma unroll
  for (int i = 0; i < 4; ++i) {
    const ushort* qptr = qb + ((size_t)h * LL + q0 + i * 16 + lr) * DD + lg * 8;
    qa[i][0] = *(const s16x8*)qptr;
    qa[i][1] = *(const s16x8*)(qptr + 32);
  }

  // ones B-fragment for rowsum MFMA
  s16x8 ones;
#pragma unroll
  for (int i = 0; i < 8; ++i) ones[i] = (short)0x3F80;

  f32x4 o[4][4] = {};
  f32x4 ol[4] = {};

  const ushort* kh = kb + (size_t)h * KVL * DD + (size_t)sp * NT * 8192;
  const ushort* vh = vbT + (size_t)h * 128 * 4096 + (size_t)sp * NT * 8192;

  // proven 64-kv body (pure function of the two LDS half-tile pointers)
  auto body = [&](const ushort* Kc, const ushort* Vc) {
    // S^T = K Q^T : 32 MFMA. Each K fragment feeds 4 row-block chains.
    f32x4 s[4][4] = {};
    __builtin_amdgcn_s_setprio(1);
#pragma unroll
    for (int k0 = 0; k0 < 2; ++k0) {
#pragma unroll
      for (int j = 0; j < 4; ++j) {
        int r = j * 16 + lr;
        s16x8 kf = *(const s16x8*)&Kc[r * 64 + (((k0 * 4 + lg) ^ (r & 7)) << 3)];
#pragma unroll
        for (int i = 0; i < 4; ++i)
          s[i][j] = __builtin_amdgcn_mfma_f32_16x16x32_bf16(kf, qa[i][k0], s[i][j], 0, 0, 0);
      }
    }
    __builtin_amdgcn_s_setprio(0);

    // P = exp2(S) (Q pre-scaled, static max), pack to bf16 pairs in-register
    uint w[4][4][2];
#pragma unroll
    for (int i = 0; i < 4; ++i)
#pragma unroll
      for (int j = 0; j < 4; ++j) {
        float p0 = fexp2(s[i][j][0]);
        float p1 = fexp2(s[i][j][1]);
        float p2 = fexp2(s[i][j][2]);
        float p3 = fexp2(s[i][j][3]);
        w[i][j][0] = cvtpk(p0, p1);
        w[i][j][1] = cvtpk(p2, p3);
      }

    // O += P V (32 MFMA) and rowsum l += P·1 (8 MFMA); V frag reused 4x
    __builtin_amdgcn_s_setprio(1);
#pragma unroll
    for (int k0 = 0; k0 < 2; ++k0) {
      s16x8 pa[4];
#pragma unroll
      for (int i = 0; i < 4; ++i) {
        uint4 u;
        u.x = w[i][2 * k0][0]; u.y = w[i][2 * k0][1];
        u.z = w[i][2 * k0 + 1][0]; u.w = w[i][2 * k0 + 1][1];
        pa[i] = __builtin_bit_cast(s16x8, u);
        ol[i] = __builtin_amdgcn_mfma_f32_16x16x32_bf16(pa[i], ones, ol[i], 0, 0, 0);
      }
#pragma unroll
      for (int j = 0; j < 4; ++j) {
        int r = j * 16 + lr;  // d row in V^T
        s16x8 bv = *(const s16x8*)&Vc[r * 64 + (((k0 * 4 + lg) ^ (r & 7)) << 3)];
#pragma unroll
        for (int i = 0; i < 4; ++i)
          o[i][j] = __builtin_amdgcn_mfma_f32_16x16x32_bf16(pa[i], bv, o[i][j], 0, 0, 0);
      }
    }
    __builtin_amdgcn_s_setprio(0);
  };

  // prologue: stage supertile 0 (4 K + 4 V gl16 per thread), wait, sync
#pragma unroll
  for (int i = 0; i < 4; ++i) {
    gl16(kh + (i * 256 + tid) * 8, &Ks[0][i * 2048 + wid * 512]);
    gl16(vh + (i * 256 + tid) * 8, &Vs[0][i * 2048 + wid * 512]);
  }
  asm volatile("s_waitcnt vmcnt(0)" ::: "memory");
  bar();

  for (int t = 0; t < NT; ++t) {
    if (t < NT - 1) {
      int nb = (t + 1) & 1;
      const ushort* gk = kh + (size_t)(t + 1) * 8192;
      const ushort* gv = vh + (size_t)(t + 1) * 8192;
#pragma unroll
      for (int i = 0; i < 4; ++i) {
        gl16(gk + (i * 256 + tid) * 8, &Ks[nb][i * 2048 + wid * 512]);
        gl16(gv + (i * 256 + tid) * 8, &Vs[nb][i * 2048 + wid * 512]);
      }
    }

    const ushort* Kc = Ks[t & 1];
    const ushort* Vc = Vs[t & 1];

    body(Kc, Vc);                    // kv half 0 (rows 0..63 of supertile)
    body(Kc + 4096, Vc + 4096);      // kv half 1 (rows 64..127)

    asm volatile("s_waitcnt vmcnt(0)" ::: "memory");  // next supertile landed
    bar();
  }

  // store unnormalized bf16 partials: row = q0 + i*16 + lg*4 + q, col = j*16 + lr
  size_t rbase = ((size_t)sp * HH + h) * LL;
#pragma unroll
  for (int i = 0; i < 4; ++i)
#pragma unroll
    for (int j = 0; j < 4; ++j)
#pragma unroll
      for (int q = 0; q < 4; ++q) {
        int row = q0 + i * 16 + lg * 4 + q;
        Op[(rbase + row) * 64 + j * 16 + lr] = f2bf(o[i][j][q]);
      }
  // rowsum: ol[i][q] identical across the 16 lr lanes; row = q0+i*16+lg*4+q
  if (lr == 0) {
#pragma unroll
    for (int i = 0; i < 4; ++i)
#pragma unroll
      for (int q = 0; q < 4; ++q)
        lb[rbase + q0 + i * 16 + lg * 4 + q] = ol[i][q];
  }
}

// ---------------- combine bf16 partials -> ctx bf16 [L][C] ----------------
__global__ __launch_bounds__(256) void k_comb(
    const ushort* __restrict__ Op, const float* __restrict__ lb,
    ushort* __restrict__ ctx, int nsp) {
  int t = threadIdx.x;
  int h = blockIdx.y;
  int row = blockIdx.x * 64 + (t >> 2);
  int d0 = (t & 3) * 16;

  float Lsum = 0.f;
  for (int s = 0; s < nsp; ++s)
    Lsum += lb[((size_t)s * HH + h) * LL + row];
  float inv = 1.0f / Lsum;

  float acc[16] = {};
  for (int s = 0; s < nsp; ++s) {
    size_t rb = (((size_t)s * HH + h) * LL + row) * 64 + d0;
    ushort tmp[16];
    *(uint4*)(tmp + 0) = *(const uint4*)(Op + rb + 0);
    *(uint4*)(tmp + 8) = *(const uint4*)(Op + rb + 8);
#pragma unroll
    for (int i = 0; i < 16; ++i) acc[i] += bf2f(tmp[i]);
  }
  ushort ob[16];
#pragma unroll
  for (int i = 0; i < 16; ++i) ob[i] = f2bf(acc[i] * inv);
  ushort* dst = ctx + (size_t)row * CC + h * 64 + d0;
  *(uint4*)(dst + 0) = *(uint4*)(ob + 0);
  *(uint4*)(dst + 8) = *(uint4*)(ob + 8);
}

extern "C" void kernel_launch(void* const* d_in, const int* in_sizes, int n_in,
                              void* d_out, int out_size, void* d_ws, size_t ws_size,
                              hipStream_t stream) {
  const float* hs  = (const float*)d_in[0];
  const float* Kbg = (const float*)d_in[1];
  const float* Vbg = (const float*)d_in[2];
  const float* Wq  = (const float*)d_in[3];
  const float* Wk  = (const float*)d_in[4];
  const float* Wv  = (const float*)d_in[5];
  const float* Wo  = (const float*)d_in[6];
  const float* bo  = (const float*)d_in[7];
  float* out = (float*)d_out;

  // fixed-layout scratch
  char* p = (char*)d_ws;
  ushort* hs_b = (ushort*)p; p += (size_t)LL * CC * 2;
  ushort* WqT  = (ushort*)p; p += (size_t)CC * CC * 2;   // WqT..WoT contiguous
  ushort* WkT  = (ushort*)p; p += (size_t)CC * CC * 2;
  ushort* WvT  = (ushort*)p; p += (size_t)CC * CC * 2;
  ushort* WoT  = (ushort*)p; p += (size_t)CC * CC * 2;
  ushort* qb   = (ushort*)p; p += (size_t)HH * LL * DD * 2;
  ushort* kb   = (ushort*)p; p += (size_t)HH * KVL * DD * 2;
  ushort* vbT  = (ushort*)p; p += (size_t)HH * KVL * DD * 2;
  ushort* ctxb = (ushort*)p; p += (size_t)LL * CC * 2;
  (void)WkT; (void)WvT;

  int nsp = 8;
  ushort* Opart = (ushort*)p; p += (size_t)nsp * HH * LL * DD * 2;
  float* lbuf   = (float*)p;  p += (size_t)nsp * HH * LL * 4;
  int NT = KVL / nsp / 128;  // supertiles (128 kv each) per split

  int n4hs = LL * CC / 4;
  k_cvt_hs<<<(n4hs + 255) / 256, 256, 0, stream>>>(hs, hs_b, n4hs);
  k_wT4<<<dim3(CC / 64, CC / 64, 4), 256, 0, stream>>>(Wq, Wk, Wv, Wo, WqT);
  int n4bg = HH * LL * DD / 4;
  k_cvt_bgK<<<(n4bg + 255) / 256, 256, 0, stream>>>(Kbg, kb, n4bg);
  k_cvt_bgV<<<dim3(64, HH), 256, 0, stream>>>(Vbg, vbT);

  k_gemmQKV<<<dim3(LL / 128, CC / 64, 3), 512, 0, stream>>>(hs_b, WqT, qb, kb, vbT);

  k_attn<<<dim3(16 * HH * nsp), 256, 0, stream>>>(qb, kb, vbT, Opart, lbuf, nsp, NT);
  k_comb<<<dim3(LL / 64, HH), 256, 0, stream>>>(Opart, lbuf, ctxb, nsp);

  k_gemmO<<<dim3(LL / 128, CC / 64), 512, 0, stream>>>(ctxb, WoT, out, bo);
}

// Round 19
// 135.307 us; speedup vs baseline: 1.1551x; 1.0540x over previous
//
#include <hip/hip_runtime.h>
#include <stdint.h>

#define HH 10
#define DD 64
#define LL 4096
#define CC 640
#define KVL 8192
#define ALPHA 0.42f
#define SC2 0.1803368801111204f  // (1/sqrt(64)) * log2(e)

typedef __attribute__((ext_vector_type(8))) short s16x8;
typedef __attribute__((ext_vector_type(4))) float f32x4;

__device__ inline ushort f2bf(float f) {
  uint32_t u = __builtin_bit_cast(uint32_t, f);
  u += 0x7FFFu + ((u >> 16) & 1u);   // RNE
  return (ushort)(u >> 16);
}

__device__ inline float bf2f(ushort u) {
  uint32_t x = (uint32_t)u << 16;
  return __builtin_bit_cast(float, x);
}

__device__ inline uint cvtpk(float lo, float hi) {
  uint r;
  asm("v_cvt_pk_bf16_f32 %0, %1, %2" : "=v"(r) : "v"(lo), "v"(hi));
  return r;
}

__device__ inline float fexp2(float x) {
  float r;
  asm("v_exp_f32 %0, %1" : "=v"(r) : "v"(x));  // pure, schedulable
  return r;
}

__device__ inline void gl16(const ushort* g, ushort* l) {
  __builtin_amdgcn_global_load_lds(
      (const __attribute__((address_space(1))) uint32_t*)g,
      (__attribute__((address_space(3))) uint32_t*)l, 16, 0, 0);
}

__device__ inline void bar() {
  __builtin_amdgcn_sched_barrier(0);
  __builtin_amdgcn_s_barrier();
  __builtin_amdgcn_sched_barrier(0);
}

// V^T tile column position for kv-local row kl (0..63), matching the
// register layout of the swapped-QK^T P fragment (see k_attn):
// A-slot s=8*lg+m (within 32-block k0) must hold kv = 32*k0+16*(m>>2)+4*lg+(m&3).
// Inverse: p = (kl&32) | ((kl&12)<<1) | ((kl&16)>>2) | (kl&3)
__device__ inline int vpos(int kl) {
  return (kl & 32) | ((kl & 12) << 1) | ((kl & 16) >> 2) | (kl & 3);
}
// bit-inverse of vpos
__device__ inline int vposInv(int c) {
  return (c & 32) | ((c & 24) >> 1) | ((c & 4) << 2) | (c & 3);
}

// ---------------- merged prep: hs cvt | bg K+V | W transpose ----------------
// flat grid 3600 x 256:
//   b <  2560 : hs fp32 -> bf16 (i = b*256+tid, exactly covers LL*CC/4)
//   b <  3200 : background K rows + V^T tile for (tt, h)
//   else      : one 64x64 W-transpose tile (z = which weight)
__global__ __launch_bounds__(256) void k_prep(
    const float* __restrict__ hs, const float* __restrict__ Kbg,
    const float* __restrict__ Vbg,
    const float* __restrict__ W0, const float* __restrict__ W1,
    const float* __restrict__ W2, const float* __restrict__ W3,
    ushort* __restrict__ hs_b, ushort* __restrict__ kb,
    ushort* __restrict__ vbT, ushort* __restrict__ WT) {
  __shared__ ushort t[64][66];
  int b = blockIdx.x;
  int tid = threadIdx.x;

  if (b < 2560) {  // ---- hs convert ----
    int i = b * 256 + tid;
    float4 v = ((const float4*)hs)[i];
    ushort4 o;
    o.x = f2bf(v.x); o.y = f2bf(v.y); o.z = f2bf(v.z); o.w = f2bf(v.w);
    ((ushort4*)hs_b)[i] = o;
    return;
  }

  if (b < 3200) {  // ---- background KV tile (64 rows x 64 d) ----
    int bb = b - 2560;
    int tt = bb & 63;          // bg tile -> global tile 64+tt
    int h = bb >> 6;
    // K rows: row-swizzled 16B chunks (verbatim k_cvt_bgK math)
#pragma unroll
    for (int k = 0; k < 4; ++k) {
      int id = tid + k * 256;
      int r = id >> 4, c4 = id & 15;
      int d0 = c4 * 4;
      int kv = LL + tt * 64 + r;
      float4 kf = *(const float4*)(Kbg + ((size_t)h * LL + tt * 64 + r) * DD + d0);
      int chunk = d0 >> 3, off = d0 & 7;
      size_t kdst = ((size_t)h * KVL + kv) * 64 + (size_t)(((chunk ^ (kv & 7)) << 3) + off);
      ushort4 ok;
      ok.x = f2bf(ALPHA * kf.x); ok.y = f2bf(ALPHA * kf.y);
      ok.z = f2bf(ALPHA * kf.z); ok.w = f2bf(ALPHA * kf.w);
      *(ushort4*)(kb + kdst) = ok;
    }
    // V tile -> LDS (verbatim k_cvt_bgV)
#pragma unroll
    for (int k = 0; k < 4; ++k) {
      int id = tid + k * 256;
      int r = id >> 4, c4 = id & 15;
      float4 v = *(const float4*)(Vbg + ((size_t)h * LL + tt * 64 + r) * DD + c4 * 4);
      t[r][c4 * 4 + 0] = f2bf(ALPHA * v.x);
      t[r][c4 * 4 + 1] = f2bf(ALPHA * v.y);
      t[r][c4 * 4 + 2] = f2bf(ALPHA * v.z);
      t[r][c4 * 4 + 3] = f2bf(ALPHA * v.w);
    }
    __syncthreads();
    int d = tid >> 2;
    int p0 = (tid & 3) * 16;
    ushort tmp[16];
#pragma unroll
    for (int pp = 0; pp < 16; ++pp) {
      int pos = p0 + pp;
      int c = (((pos >> 3) ^ (d & 7)) << 3) | (pos & 7);
      tmp[pp] = t[vposInv(c)][d];
    }
    ushort* dst = vbT + ((size_t)h * 128 + 64 + tt) * 4096 + d * 64 + p0;
    *(uint4*)(dst + 0) = *(uint4*)(tmp + 0);
    *(uint4*)(dst + 8) = *(uint4*)(tmp + 8);
    return;
  }

  // ---- W transpose tile (verbatim k_wT4 body) ----
  {
    int bw = b - 3200;          // 0..399
    int z = bw / 100;
    int rem = bw - z * 100;
    int k0 = (rem / 10) * 64, n0 = (rem % 10) * 64;
    const float* W = z == 0 ? W0 : z == 1 ? W1 : z == 2 ? W2 : W3;
    ushort* dst = WT + (size_t)z * CC * CC;
#pragma unroll
    for (int i = 0; i < 4; ++i) {
      int id = tid + i * 256;
      int r = id >> 4, c4 = id & 15;
      float4 v = *(const float4*)(W + (size_t)(k0 + r) * CC + n0 + c4 * 4);
      t[r][c4 * 4 + 0] = f2bf(v.x);
      t[r][c4 * 4 + 1] = f2bf(v.y);
      t[r][c4 * 4 + 2] = f2bf(v.z);
      t[r][c4 * 4 + 3] = f2bf(v.w);
    }
    __syncthreads();
#pragma unroll
    for (int i = 0; i < 2; ++i) {
      int id = tid + i * 256;
      int n = id >> 3, cc = id & 7;
      ushort tmp[8];
#pragma unroll
      for (int j = 0; j < 8; ++j) tmp[j] = t[cc * 8 + j][n];
      *(uint4*)(dst + (size_t)(n0 + n) * CC + k0 + cc * 8) = *(uint4*)tmp;
    }
  }
}

// ---------------- fused QKV GEMM: z selects weight slice + epilogue ----------------
__global__ __launch_bounds__(512) void k_gemmQKV(
    const ushort* __restrict__ A, const ushort* __restrict__ WT,
    ushort* __restrict__ qb, ushort* __restrict__ kb, ushort* __restrict__ vbT) {
  __shared__ uint4 As4[128 * 8];
  __shared__ uint4 Bs4[64 * 8];
  int tid = threadIdx.x;
  int m0 = blockIdx.x * 128, n0 = blockIdx.y * 64;
  int z = blockIdx.z;
  const ushort* BT = WT + (size_t)z * CC * CC;
  int wid = tid >> 6, lane = tid & 63;
  int wr = wid >> 1, wc = wid & 1;
  int lr = lane & 15, lg = lane >> 4;
  f32x4 acc[2][2] = {};

  for (int kt = 0; kt < CC; kt += 64) {
    __syncthreads();
    {
      int id = tid;
#pragma unroll
      for (int i = 0; i < 2; ++i, id += 512) {
        int r = id >> 3, cc = id & 7;
        uint4 v = *(const uint4*)(A + (size_t)(m0 + r) * CC + kt + cc * 8);
        As4[r * 8 + (cc ^ (r & 7))] = v;
      }
      int r = tid >> 3, cc = tid & 7;
      uint4 v = *(const uint4*)(BT + (size_t)(n0 + r) * CC + kt + cc * 8);
      Bs4[r * 8 + (cc ^ (r & 7))] = v;
    }
    __syncthreads();
#pragma unroll
    for (int k0 = 0; k0 < 2; ++k0) {
      s16x8 a[2], b[2];
#pragma unroll
      for (int i = 0; i < 2; ++i) {
        int r = wr * 32 + i * 16 + lr;
        a[i] = *(const s16x8*)&As4[r * 8 + ((k0 * 4 + lg) ^ (r & 7))];
      }
#pragma unroll
      for (int j = 0; j < 2; ++j) {
        int r = wc * 32 + j * 16 + lr;
        b[j] = *(const s16x8*)&Bs4[r * 8 + ((k0 * 4 + lg) ^ (r & 7))];
      }
#pragma unroll
      for (int i = 0; i < 2; ++i)
#pragma unroll
        for (int j = 0; j < 2; ++j)
          acc[i][j] = __builtin_amdgcn_mfma_f32_16x16x32_bf16(a[i], b[j], acc[i][j], 0, 0, 0);
    }
  }
#pragma unroll
  for (int i = 0; i < 2; ++i)
#pragma unroll
    for (int j = 0; j < 2; ++j)
#pragma unroll
      for (int q = 0; q < 4; ++q) {
        int m = m0 + wr * 32 + i * 16 + lg * 4 + q;
        int n = n0 + wc * 32 + j * 16 + lr;
        float v = acc[i][j][q];
        if (z == 0) {        // Q: head layout, scaled by SC2
          qb[(size_t)(n >> 6) * ((size_t)LL * DD) + (size_t)m * 64 + (n & 63)] = f2bf(v * SC2);
        } else if (z == 1) { // K: row-swizzled
          int d = n & 63;
          kb[(size_t)(n >> 6) * ((size_t)KVL * DD) + (size_t)m * 64 +
             (((d >> 3) ^ (m & 7)) << 3) + (d & 7)] = f2bf(v);
        } else {             // V: V^T permuted tiles
          int d = n & 63, tile = m >> 6, kl = m & 63;
          int c = vpos(kl);
          vbT[((size_t)(n >> 6) * 128 + tile) * 4096 + (size_t)d * 64 +
              (((c >> 3) ^ (d & 7)) << 3) + (c & 7)] = f2bf(v);
        }
      }
}

// ---------------- final GEMM: fp32 + bias ----------------
__global__ __launch_bounds__(512) void k_gemmO(
    const ushort* __restrict__ A, const ushort* __restrict__ BT,
    float* __restrict__ outF, const float* __restrict__ bias) {
  __shared__ uint4 As4[128 * 8];
  __shared__ uint4 Bs4[64 * 8];
  int tid = threadIdx.x;
  int m0 = blockIdx.x * 128, n0 = blockIdx.y * 64;
  int wid = tid >> 6, lane = tid & 63;
  int wr = wid >> 1, wc = wid & 1;
  int lr = lane & 15, lg = lane >> 4;
  f32x4 acc[2][2] = {};

  for (int kt = 0; kt < CC; kt += 64) {
    __syncthreads();
    {
      int id = tid;
#pragma unroll
      for (int i = 0; i < 2; ++i, id += 512) {
        int r = id >> 3, cc = id & 7;
        uint4 v = *(const uint4*)(A + (size_t)(m0 + r) * CC + kt + cc * 8);
        As4[r * 8 + (cc ^ (r & 7))] = v;
      }
      int r = tid >> 3, cc = tid & 7;
      uint4 v = *(const uint4*)(BT + (size_t)(n0 + r) * CC + kt + cc * 8);
      Bs4[r * 8 + (cc ^ (r & 7))] = v;
    }
    __syncthreads();
#pragma unroll
    for (int k0 = 0; k0 < 2; ++k0) {
      s16x8 a[2], b[2];
#pragma unroll
      for (int i = 0; i < 2; ++i) {
        int r = wr * 32 + i * 16 + lr;
        a[i] = *(const s16x8*)&As4[r * 8 + ((k0 * 4 + lg) ^ (r & 7))];
      }
#pragma unroll
      for (int j = 0; j < 2; ++j) {
        int r = wc * 32 + j * 16 + lr;
        b[j] = *(const s16x8*)&Bs4[r * 8 + ((k0 * 4 + lg) ^ (r & 7))];
      }
#pragma unroll
      for (int i = 0; i < 2; ++i)
#pragma unroll
        for (int j = 0; j < 2; ++j)
          acc[i][j] = __builtin_amdgcn_mfma_f32_16x16x32_bf16(a[i], b[j], acc[i][j], 0, 0, 0);
    }
  }
#pragma unroll
  for (int i = 0; i < 2; ++i)
#pragma unroll
    for (int j = 0; j < 2; ++j)
#pragma unroll
      for (int q = 0; q < 4; ++q) {
        int m = m0 + wr * 32 + i * 16 + lg * 4 + q;
        int n = n0 + wc * 32 + j * 16 + lr;
        outF[(size_t)m * CC + n] = acc[i][j][q] + bias[n];
      }
}

// ---------------- flash attention (KV-split, static max, in-register P) ----------------
// R15/R17-proven supertile schedule (nsp=8), bf16 partials.
__global__ __launch_bounds__(256, 2) void k_attn(
    const ushort* __restrict__ qb,    // [H][L][64], pre-scaled by SC2
    const ushort* __restrict__ kb,    // [H][KVL][64] row-swizzled
    const ushort* __restrict__ vbT,   // [H][128][4096] V^T permuted tiles
    ushort* __restrict__ Op,          // [nsp][H][L][64] unnormalized bf16
    float* __restrict__ lb,           // [nsp][H][L] row sums
    int nsp, int NT) {                // split count, SUPERTILES per split
  __shared__ ushort Ks[2][8192];
  __shared__ ushort Vs[2][8192];

  int tid = threadIdx.x, wid = tid >> 6, lane = tid & 63;
  int lr = lane & 15, lg = lane >> 4;

  // XCD-contiguous remap
  int flat = blockIdx.x;
  int span = 20 * nsp;               // grid/8
  int f2 = (flat & 7) * span + (flat >> 3);
  int qblk = f2 & 15;
  int hs2 = f2 >> 4;                 // 0..10*nsp-1
  int h = hs2 % HH;
  int sp = hs2 / HH;
  int q0 = qblk * 256 + wid * 64;

  // Q fragments: 4 row-blocks x 2 k-chunks
  s16x8 qa[4][2];
#pragma unroll
  for (int i = 0; i < 4; ++i) {
    const ushort* qptr = qb + ((size_t)h * LL + q0 + i * 16 + lr) * DD + lg * 8;
    qa[i][0] = *(const s16x8*)qptr;
    qa[i][1] = *(const s16x8*)(qptr + 32);
  }

  // ones B-fragment for rowsum MFMA
  s16x8 ones;
#pragma unroll
  for (int i = 0; i < 8; ++i) ones[i] = (short)0x3F80;

  f32x4 o[4][4] = {};
  f32x4 ol[4] = {};

  const ushort* kh = kb + (size_t)h * KVL * DD + (size_t)sp * NT * 8192;
  const ushort* vh = vbT + (size_t)h * 128 * 4096 + (size_t)sp * NT * 8192;

  // proven 64-kv body (pure function of the two LDS half-tile pointers)
  auto body = [&](const ushort* Kc, const ushort* Vc) {
    f32x4 s[4][4] = {};
    __builtin_amdgcn_s_setprio(1);
#pragma unroll
    for (int k0 = 0; k0 < 2; ++k0) {
#pragma unroll
      for (int j = 0; j < 4; ++j) {
        int r = j * 16 + lr;
        s16x8 kf = *(const s16x8*)&Kc[r * 64 + (((k0 * 4 + lg) ^ (r & 7)) << 3)];
#pragma unroll
        for (int i = 0; i < 4; ++i)
          s[i][j] = __builtin_amdgcn_mfma_f32_16x16x32_bf16(kf, qa[i][k0], s[i][j], 0, 0, 0);
      }
    }
    __builtin_amdgcn_s_setprio(0);

    uint w[4][4][2];
#pragma unroll
    for (int i = 0; i < 4; ++i)
#pragma unroll
      for (int j = 0; j < 4; ++j) {
        float p0 = fexp2(s[i][j][0]);
        float p1 = fexp2(s[i][j][1]);
        float p2 = fexp2(s[i][j][2]);
        float p3 = fexp2(s[i][j][3]);
        w[i][j][0] = cvtpk(p0, p1);
        w[i][j][1] = cvtpk(p2, p3);
      }

    __builtin_amdgcn_s_setprio(1);
#pragma unroll
    for (int k0 = 0; k0 < 2; ++k0) {
      s16x8 pa[4];
#pragma unroll
      for (int i = 0; i < 4; ++i) {
        uint4 u;
        u.x = w[i][2 * k0][0]; u.y = w[i][2 * k0][1];
        u.z = w[i][2 * k0 + 1][0]; u.w = w[i][2 * k0 + 1][1];
        pa[i] = __builtin_bit_cast(s16x8, u);
        ol[i] = __builtin_amdgcn_mfma_f32_16x16x32_bf16(pa[i], ones, ol[i], 0, 0, 0);
      }
#pragma unroll
      for (int j = 0; j < 4; ++j) {
        int r = j * 16 + lr;  // d row in V^T
        s16x8 bv = *(const s16x8*)&Vc[r * 64 + (((k0 * 4 + lg) ^ (r & 7)) << 3)];
#pragma unroll
        for (int i = 0; i < 4; ++i)
          o[i][j] = __builtin_amdgcn_mfma_f32_16x16x32_bf16(pa[i], bv, o[i][j], 0, 0, 0);
      }
    }
    __builtin_amdgcn_s_setprio(0);
  };

  // prologue: stage supertile 0 (4 K + 4 V gl16 per thread), wait, sync
#pragma unroll
  for (int i = 0; i < 4; ++i) {
    gl16(kh + (i * 256 + tid) * 8, &Ks[0][i * 2048 + wid * 512]);
    gl16(vh + (i * 256 + tid) * 8, &Vs[0][i * 2048 + wid * 512]);
  }
  asm volatile("s_waitcnt vmcnt(0)" ::: "memory");
  bar();

  for (int t = 0; t < NT; ++t) {
    if (t < NT - 1) {
      int nb = (t + 1) & 1;
      const ushort* gk = kh + (size_t)(t + 1) * 8192;
      const ushort* gv = vh + (size_t)(t + 1) * 8192;
#pragma unroll
      for (int i = 0; i < 4; ++i) {
        gl16(gk + (i * 256 + tid) * 8, &Ks[nb][i * 2048 + wid * 512]);
        gl16(gv + (i * 256 + tid) * 8, &Vs[nb][i * 2048 + wid * 512]);
      }
    }

    const ushort* Kc = Ks[t & 1];
    const ushort* Vc = Vs[t & 1];

    body(Kc, Vc);                    // kv half 0 (rows 0..63 of supertile)
    body(Kc + 4096, Vc + 4096);      // kv half 1 (rows 64..127)

    asm volatile("s_waitcnt vmcnt(0)" ::: "memory");  // next supertile landed
    bar();
  }

  // store unnormalized bf16 partials
  size_t rbase = ((size_t)sp * HH + h) * LL;
#pragma unroll
  for (int i = 0; i < 4; ++i)
#pragma unroll
    for (int j = 0; j < 4; ++j)
#pragma unroll
      for (int q = 0; q < 4; ++q) {
        int row = q0 + i * 16 + lg * 4 + q;
        Op[(rbase + row) * 64 + j * 16 + lr] = f2bf(o[i][j][q]);
      }
  if (lr == 0) {
#pragma unroll
    for (int i = 0; i < 4; ++i)
#pragma unroll
      for (int q = 0; q < 4; ++q)
        lb[rbase + q0 + i * 16 + lg * 4 + q] = ol[i][q];
  }
}

// ---------------- combine bf16 partials -> ctx bf16 [L][C] ----------------
__global__ __launch_bounds__(256) void k_comb(
    const ushort* __restrict__ Op, const float* __restrict__ lb,
    ushort* __restrict__ ctx, int nsp) {
  int t = threadIdx.x;
  int h = blockIdx.y;
  int row = blockIdx.x * 64 + (t >> 2);
  int d0 = (t & 3) * 16;

  float Lsum = 0.f;
  for (int s = 0; s < nsp; ++s)
    Lsum += lb[((size_t)s * HH + h) * LL + row];
  float inv = 1.0f / Lsum;

  float acc[16] = {};
  for (int s = 0; s < nsp; ++s) {
    size_t rb = (((size_t)s * HH + h) * LL + row) * 64 + d0;
    ushort tmp[16];
    *(uint4*)(tmp + 0) = *(const uint4*)(Op + rb + 0);
    *(uint4*)(tmp + 8) = *(const uint4*)(Op + rb + 8);
#pragma unroll
    for (int i = 0; i < 16; ++i) acc[i] += bf2f(tmp[i]);
  }
  ushort ob[16];
#pragma unroll
  for (int i = 0; i < 16; ++i) ob[i] = f2bf(acc[i] * inv);
  ushort* dst = ctx + (size_t)row * CC + h * 64 + d0;
  *(uint4*)(dst + 0) = *(uint4*)(ob + 0);
  *(uint4*)(dst + 8) = *(uint4*)(ob + 8);
}

extern "C" void kernel_launch(void* const* d_in, const int* in_sizes, int n_in,
                              void* d_out, int out_size, void* d_ws, size_t ws_size,
                              hipStream_t stream) {
  const float* hs  = (const float*)d_in[0];
  const float* Kbg = (const float*)d_in[1];
  const float* Vbg = (const float*)d_in[2];
  const float* Wq  = (const float*)d_in[3];
  const float* Wk  = (const float*)d_in[4];
  const float* Wv  = (const float*)d_in[5];
  const float* Wo  = (const float*)d_in[6];
  const float* bo  = (const float*)d_in[7];
  float* out = (float*)d_out;

  // fixed-layout scratch
  char* p = (char*)d_ws;
  ushort* hs_b = (ushort*)p; p += (size_t)LL * CC * 2;
  ushort* WqT  = (ushort*)p; p += (size_t)CC * CC * 2;   // WqT..WoT contiguous
  ushort* WkT  = (ushort*)p; p += (size_t)CC * CC * 2;
  ushort* WvT  = (ushort*)p; p += (size_t)CC * CC * 2;
  ushort* WoT  = (ushort*)p; p += (size_t)CC * CC * 2;
  ushort* qb   = (ushort*)p; p += (size_t)HH * LL * DD * 2;
  ushort* kb   = (ushort*)p; p += (size_t)HH * KVL * DD * 2;
  ushort* vbT  = (ushort*)p; p += (size_t)HH * KVL * DD * 2;
  ushort* ctxb = (ushort*)p; p += (size_t)LL * CC * 2;
  (void)WkT; (void)WvT;

  int nsp = 8;
  ushort* Opart = (ushort*)p; p += (size_t)nsp * HH * LL * DD * 2;
  float* lbuf   = (float*)p;  p += (size_t)nsp * HH * LL * 4;
  int NT = KVL / nsp / 128;  // supertiles (128 kv each) per split

  // merged prep: hs cvt (2560 blocks) + bg KV (640) + W transpose (400)
  k_prep<<<dim3(3600), 256, 0, stream>>>(hs, Kbg, Vbg, Wq, Wk, Wv, Wo,
                                         hs_b, kb, vbT, WqT);

  k_gemmQKV<<<dim3(LL / 128, CC / 64, 3), 512, 0, stream>>>(hs_b, WqT, qb, kb, vbT);

  k_attn<<<dim3(16 * HH * nsp), 256, 0, stream>>>(qb, kb, vbT, Opart, lbuf, nsp, NT);
  k_comb<<<dim3(LL / 64, HH), 256, 0, stream>>>(Opart, lbuf, ctxb, nsp);

  k_gemmO<<<dim3(LL / 128, CC / 64), 512, 0, stream>>>(ctxb, WoT, out, bo);
}